// Round 24
// baseline (995.951 us; speedup 1.0000x reference)
//
#pragma clang fp contract(off)
#include <hip/hip_runtime.h>
#include <math.h>

// GRUCell + LN, B=16384, IN=H=512, fp32. PASSED numerics recipe (R19+):
//  * GEMM dots: per-element ONE ascending fused-FMA chain over k=0..511.
//  * hh-LN: unseeded symmetric pairwise sum512=(B0+B1)+(B2+B3), B=128-elem
//    npyv-AVX512 base; mean=sum/512; rstd=correctly-rounded (var+1e-5f)^-0.5.
//  * v=((hh-mu)*rstd)*g+b; tan via f64; out=(z*h)+((1-z)*th).
//  * z path relaxed (contraction-bounded).
//
// R25 = R24 with the VOP3P operand bug fixed: v_pk_fma_f32 sources must be
// VGPR PAIRS. Weight scalar now comes from an aligned f32x2 sub-pair of the
// float4 load, broadcast via op_sel (no movs):
//   pkfma_lo: op_sel:[0,0,0] op_sel_hi:[1,0,1]  (broadcast w.lo)
//   pkfma_hi: op_sel:[0,1,0] op_sel_hi:[1,1,1]  (broadcast w.hi)
// Per-half IEEE fused, same ascending-k order => bit-exact.
// Occupancy fix retained: 8 rows/block, 32KB LDS => 4+ blocks/CU.

#define TPB 512
typedef float f32x2 __attribute__((ext_vector_type(2)));
typedef float f32x4 __attribute__((ext_vector_type(4)));

// acc = a * broadcast(w.lo) + acc   (per-half fused)
__device__ __forceinline__ void pkfma_lo(f32x2& acc, f32x2 a, f32x2 w) {
    asm("v_pk_fma_f32 %0, %1, %2, %0 op_sel:[0,0,0] op_sel_hi:[1,0,1]"
        : "+v"(acc) : "v"(a), "v"(w));
}
// acc = a * broadcast(w.hi) + acc
__device__ __forceinline__ void pkfma_hi(f32x2& acc, f32x2 a, f32x2 w) {
    asm("v_pk_fma_f32 %0, %1, %2, %0 op_sel:[0,1,0] op_sel_hi:[1,1,1]"
        : "+v"(acc) : "v"(a), "v"(w));
}

// ---- numpy npyv-AVX512 pairwise base, n == 128 exactly ----
__device__ __forceinline__ float pw_avx512_128(const float* a) {
    float L[16];
#pragma unroll
    for (int l = 0; l < 16; ++l)
        L[l] = ((a[l] + a[16 + l]) + (a[32 + l] + a[48 + l]))
             + ((a[64 + l] + a[80 + l]) + (a[96 + l] + a[112 + l]));
    float s[8];
#pragma unroll
    for (int i = 0; i < 8; ++i) s[i] = L[i] + L[i + 8];
    float q[4];
#pragma unroll
    for (int i = 0; i < 4; ++i) q[i] = s[i] + s[i + 4];
    return (q[0] + q[2]) + (q[1] + q[3]);
}
__device__ float np_row_sum512(const float* a) {
    return (pw_avx512_128(a) + pw_avx512_128(a + 128))
         + (pw_avx512_128(a + 256) + pw_avx512_128(a + 384));
}

// ---- weight transpose: P[m][k4][j][kk] = W_m[j][4*k4+kk] ----
__global__ __launch_bounds__(256) void k_tr(
    const float* __restrict__ Wr, const float* __restrict__ Ur,
    const float* __restrict__ Uh, const float* __restrict__ Wh,
    const float* __restrict__ Wz, const float* __restrict__ Uz,
    float* __restrict__ P)
{
    const int idx = blockIdx.x * 256 + threadIdx.x;   // 6*65536 total
    const int m = idx >> 16;
    const int t = idx & 65535;
    const int k4 = t >> 9, j = t & 511;
    const float* W = (m == 0) ? Wr : (m == 1) ? Ur : (m == 2) ? Uh
                   : (m == 3) ? Wh : (m == 4) ? Wz : Uz;
    const float4 v = *(const float4*)(W + ((size_t)j << 9) + (k4 << 2));
    *(float4*)(P + ((size_t)m << 18) + (k4 << 11) + (j << 2)) = v;
}

// ================= fast kernel: 8 rows/block =================
__global__ __launch_bounds__(TPB) void gru_fast(
    const float* __restrict__ x,  const float* __restrict__ h,
    const float* __restrict__ P,
    const float* __restrict__ bz, const float* __restrict__ buz,
    const float* __restrict__ br, const float* __restrict__ bur,
    const float* __restrict__ bh, const float* __restrict__ buh,
    const float* __restrict__ ln_g, const float* __restrict__ ln_b,
    float* __restrict__ out)
{
    __shared__ union {
        struct { float xs2[4][1024]; float hs2[4][1024]; } a;        // 32 KB
        struct { float hha[8][516]; float lnB[8][4];
                 float zsum[8][8]; float zsq[8][8];
                 float mu[8]; float rstd[8]; float muz[8]; float rstdz[8]; } b;
    } L;

    const int j  = threadIdx.x;
    const int r0 = blockIdx.x * 8;

    {   // stage 8 x,h rows pair-interleaved: xs2[rp][2k+half] = x[2rp+half][k]
        const float4* xg = (const float4*)(x + ((size_t)r0 << 9));
        const float4* hg = (const float4*)(h + ((size_t)r0 << 9));
        for (int i = j; i < 1024; i += TPB) {
            const int row = i >> 7, c4 = i & 127;
            const int rp = row >> 1, half = row & 1;
            const int base = rp * 1024 + c4 * 8 + half;
            const float4 vx = xg[i];
            float* xd = &L.a.xs2[0][0];
            xd[base + 0] = vx.x; xd[base + 2] = vx.y;
            xd[base + 4] = vx.z; xd[base + 6] = vx.w;
            const float4 vh = hg[i];
            float* hd = &L.a.hs2[0][0];
            hd[base + 0] = vh.x; hd[base + 2] = vh.y;
            hd[base + 4] = vh.z; hd[base + 6] = vh.w;
        }
    }
    __syncthreads();

    const float* pWr = P;
    const float* pUr = P + 262144;
    const float* pUh = P + 524288;
    const float* pWh = P + 786432;
    const float* pWz = P + 1048576;
    const float* pUz = P + 1310720;

    const float brj = br[j], burj = bur[j], buhj = buh[j], bhj = bh[j];
    const float bzj = bz[j] + buz[j];                     // relaxed

    f32x2 aWr[4], aUr[4], aUh[4], aWh[4], aZ[4];
#pragma unroll
    for (int p = 0; p < 4; ++p) {
        aWr[p] = (f32x2)0.f; aUr[p] = (f32x2)0.f; aUh[p] = (f32x2)0.f;
        aWh[p] = (f32x2)0.f; aZ[p]  = (f32x2)0.f;
    }

    // depth-1 software pipeline on the 6 weight vectors
    const int off0 = (j << 2);
    f32x4 wr = *(const f32x4*)(pWr + off0);
    f32x4 ur = *(const f32x4*)(pUr + off0);
    f32x4 uh = *(const f32x4*)(pUh + off0);
    f32x4 wh = *(const f32x4*)(pWh + off0);
    f32x4 wz = *(const f32x4*)(pWz + off0);
    f32x4 uz = *(const f32x4*)(pUz + off0);

#pragma unroll 2
    for (int k4 = 0; k4 < 128; ++k4) {
        const int kn = (k4 < 127) ? (k4 + 1) : 127;
        const int noff = (kn << 11) + (j << 2);
        const f32x4 nwr = *(const f32x4*)(pWr + noff);
        const f32x4 nur = *(const f32x4*)(pUr + noff);
        const f32x4 nuh = *(const f32x4*)(pUh + noff);
        const f32x4 nwh = *(const f32x4*)(pWh + noff);
        const f32x4 nwz = *(const f32x4*)(pWz + noff);
        const f32x4 nuz = *(const f32x4*)(pUz + noff);

        const f32x2 wrA = __builtin_shufflevector(wr, wr, 0, 1);
        const f32x2 wrB = __builtin_shufflevector(wr, wr, 2, 3);
        const f32x2 urA = __builtin_shufflevector(ur, ur, 0, 1);
        const f32x2 urB = __builtin_shufflevector(ur, ur, 2, 3);
        const f32x2 uhA = __builtin_shufflevector(uh, uh, 0, 1);
        const f32x2 uhB = __builtin_shufflevector(uh, uh, 2, 3);
        const f32x2 whA = __builtin_shufflevector(wh, wh, 0, 1);
        const f32x2 whB = __builtin_shufflevector(wh, wh, 2, 3);
        const f32x2 wzA = __builtin_shufflevector(wz, wz, 0, 1);
        const f32x2 wzB = __builtin_shufflevector(wz, wz, 2, 3);
        const f32x2 uzA = __builtin_shufflevector(uz, uz, 0, 1);
        const f32x2 uzB = __builtin_shufflevector(uz, uz, 2, 3);
#pragma unroll
        for (int p = 0; p < 4; ++p) {
            const float* xb = &L.a.xs2[p][k4 << 3];
            const float* hb = &L.a.hs2[p][k4 << 3];
            const f32x4 xA = *(const f32x4*)(xb);      // pairs k, k+1
            const f32x4 xB = *(const f32x4*)(xb + 4);  // pairs k+2, k+3
            const f32x4 hA = *(const f32x4*)(hb);
            const f32x4 hB = *(const f32x4*)(hb + 4);
            const f32x2 x0 = __builtin_shufflevector(xA, xA, 0, 1);
            const f32x2 x1 = __builtin_shufflevector(xA, xA, 2, 3);
            const f32x2 x2 = __builtin_shufflevector(xB, xB, 0, 1);
            const f32x2 x3 = __builtin_shufflevector(xB, xB, 2, 3);
            const f32x2 h0 = __builtin_shufflevector(hA, hA, 0, 1);
            const f32x2 h1 = __builtin_shufflevector(hA, hA, 2, 3);
            const f32x2 h2 = __builtin_shufflevector(hB, hB, 0, 1);
            const f32x2 h3 = __builtin_shufflevector(hB, hB, 2, 3);
            // ascending-k fused chains, identical per-row rounding order
            pkfma_lo(aWr[p], x0, wrA); pkfma_hi(aWr[p], x1, wrA);
            pkfma_lo(aWr[p], x2, wrB); pkfma_hi(aWr[p], x3, wrB);
            pkfma_lo(aUr[p], h0, urA); pkfma_hi(aUr[p], h1, urA);
            pkfma_lo(aUr[p], h2, urB); pkfma_hi(aUr[p], h3, urB);
            pkfma_lo(aUh[p], h0, uhA); pkfma_hi(aUh[p], h1, uhA);
            pkfma_lo(aUh[p], h2, uhB); pkfma_hi(aUh[p], h3, uhB);
            pkfma_lo(aWh[p], x0, whA); pkfma_hi(aWh[p], x1, whA);
            pkfma_lo(aWh[p], x2, whB); pkfma_hi(aWh[p], x3, whB);
            pkfma_lo(aZ[p],  x0, wzA); pkfma_hi(aZ[p],  x1, wzA);
            pkfma_lo(aZ[p],  x2, wzB); pkfma_hi(aZ[p],  x3, wzB);
            pkfma_lo(aZ[p],  h0, uzA); pkfma_hi(aZ[p],  h1, uzA);
            pkfma_lo(aZ[p],  h2, uzB); pkfma_hi(aZ[p],  h3, uzB);
        }
        wr = nwr; ur = nur; uh = nuh; wh = nwh; wz = nwz; uz = nuz;
    }

    // glue (exact scalar orders)
    float hh[8], zp[8];
#pragma unroll
    for (int p = 0; p < 4; ++p) {
#pragma unroll
        for (int half = 0; half < 2; ++half) {
            const float dWr = half ? aWr[p].y : aWr[p].x;
            const float dUr = half ? aUr[p].y : aUr[p].x;
            const float dUh = half ? aUh[p].y : aUh[p].x;
            const float dWh = half ? aWh[p].y : aWh[p].x;
            const float dZ  = half ? aZ[p].y  : aZ[p].x;
            const float rp2 = ((dWr + brj) + dUr) + burj;   // exact order
            const float up  = dUh + buhj;
            hh[p * 2 + half] = (dWh + bhj) + rp2 * up;
            zp[p * 2 + half] = dZ + bzj;
        }
    }
    __syncthreads();   // xs2/hs2 dead; union b becomes live

#pragma unroll
    for (int r = 0; r < 8; ++r) L.b.hha[r][j] = hh[r];
    {   // relaxed z stats: wave-level shfl reduce -> per-wave partials
        const int wid = j >> 6, lane = j & 63;
#pragma unroll
        for (int r = 0; r < 8; ++r) {
            float s = zp[r], q = zp[r] * zp[r];
#pragma unroll
            for (int o = 1; o < 64; o <<= 1) { s += __shfl_xor(s, o); q += __shfl_xor(q, o); }
            if (lane == 0) { L.b.zsum[r][wid] = s; L.b.zsq[r][wid] = q; }
        }
    }
    __syncthreads();

    // LN stage 1: 32 threads compute the four 128-blocks per row (exact base)
    if (j < 32) {
        const int r = j >> 2, b = j & 3;
        L.b.lnB[r][b] = pw_avx512_128(&L.b.hha[r][b * 128]);
    } else if (j < 40) {
        const int r = j - 32;   // relaxed z finalize
        float s = 0.f, q = 0.f;
#pragma unroll
        for (int w = 0; w < 8; ++w) { s += L.b.zsum[r][w]; q += L.b.zsq[r][w]; }
        const float m = s / 512.0f;
        L.b.muz[r]   = m;
        L.b.rstdz[r] = 1.0f / sqrtf(q / 512.0f - m * m + 1e-5f);
    }
    __syncthreads();
    if (j < 8) {
        const float sum = (L.b.lnB[j][0] + L.b.lnB[j][1])
                        + (L.b.lnB[j][2] + L.b.lnB[j][3]);   // exact tree
        L.b.mu[j] = sum / 512.0f;
    }
    __syncthreads();
#pragma unroll
    for (int r = 0; r < 8; ++r) {
        const float d = hh[r] - L.b.mu[r];
        L.b.hha[r][j] = d * d;
    }
    __syncthreads();
    if (j < 32) {
        const int r = j >> 2, b = j & 3;
        L.b.lnB[r][b] = pw_avx512_128(&L.b.hha[r][b * 128]);
    }
    __syncthreads();
    if (j < 8) {
        const float var = ((L.b.lnB[j][0] + L.b.lnB[j][1])
                         + (L.b.lnB[j][2] + L.b.lnB[j][3])) / 512.0f;
        const float ve  = var + 1e-5f;
        L.b.rstd[j] = (float)(1.0 / sqrt((double)ve));   // correctly-rounded
    }
    __syncthreads();

    const float g2 = ln_g[1024 + j], b2 = ln_b[1024 + j];
    const float g0 = ln_g[j],        b0 = ln_b[j];
#pragma unroll
    for (int r = 0; r < 8; ++r) {
        const float d  = hh[r] - L.b.mu[r];
        const float t  = d * L.b.rstd[r];
        const float v  = (t * g2) + b2;                 // exact order
        const float th = (float)tan((double)v);
        const float vz = ((zp[r] - L.b.muz[r]) * L.b.rstdz[r]) * g0 + b0;
        const float zf = 1.0f / (1.0f + expf(-vz));
        const float hv = h[((size_t)(r0 + r) << 9) + j];
        out[((size_t)(r0 + r) << 9) + j] = (zf * hv) + (1.0f - zf) * th;
    }
}

// ================= fallback (R19, proven) =================
__device__ __forceinline__ void sweep3c(const float* __restrict__ sa,
                                        const float* __restrict__ wA,
                                        const float* __restrict__ wB,
                                        const float* __restrict__ wC,
                                        float& dA, float& dB, float& dC)
{
    float a = 0.f, b = 0.f, c = 0.f;
    for (int k4 = 0; k4 < 128; ++k4) {
        const int k0 = k4 << 2;
        const float4 xv = *(const float4*)(sa + k0);
        const float4 av = *(const float4*)(wA + k0);
        const float4 bv = *(const float4*)(wB + k0);
        const float4 cv = *(const float4*)(wC + k0);
        a = fmaf(xv.x, av.x, a); a = fmaf(xv.y, av.y, a);
        a = fmaf(xv.z, av.z, a); a = fmaf(xv.w, av.w, a);
        b = fmaf(xv.x, bv.x, b); b = fmaf(xv.y, bv.y, b);
        b = fmaf(xv.z, bv.z, b); b = fmaf(xv.w, bv.w, b);
        c = fmaf(xv.x, cv.x, c); c = fmaf(xv.y, cv.y, c);
        c = fmaf(xv.z, cv.z, c); c = fmaf(xv.w, cv.w, c);
    }
    dA = a; dB = b; dC = c;
}

__global__ __launch_bounds__(TPB) void gru_np19(
    const float* __restrict__ x,  const float* __restrict__ h,
    const float* __restrict__ Wz, const float* __restrict__ bz,
    const float* __restrict__ Uz, const float* __restrict__ buz,
    const float* __restrict__ Wr, const float* __restrict__ br,
    const float* __restrict__ Ur, const float* __restrict__ bur,
    const float* __restrict__ Wh, const float* __restrict__ bh,
    const float* __restrict__ Uh, const float* __restrict__ buh,
    const float* __restrict__ ln_g, const float* __restrict__ ln_b,
    float* __restrict__ out)
{
    __shared__ union {
        float xh[2][16][512];
        struct { float hha[16][522]; float mu[16]; float rstd[16]; } ln;
    } S;
    const int tid = threadIdx.x;
    const int r = tid >> 5, jt = tid & 31;
    const int r0 = blockIdx.x * 16;
    {
        const float4* xg = (const float4*)(x + ((size_t)r0 << 9));
        const float4* hg = (const float4*)(h + ((size_t)r0 << 9));
        float4* xd = (float4*)S.xh[0];
        float4* hd = (float4*)S.xh[1];
        for (int idx = tid; idx < 2048; idx += TPB) { xd[idx] = xg[idx]; hd[idx] = hg[idx]; }
    }
    __syncthreads();
    const float* xs = S.xh[0][r];
    const float* hs = S.xh[1][r];
    float hh[16], zp[16];
    for (int jj = 0; jj < 16; ++jj) {
        const int j = jt * 16 + jj;
        const size_t jb = (size_t)j << 9;
        float dWr, dWh, zx;
        sweep3c(xs, Wr + jb, Wh + jb, Wz + jb, dWr, dWh, zx);
        float dUr, dUh, zh;
        sweep3c(hs, Ur + jb, Uh + jb, Uz + jb, dUr, dUh, zh);
        const float rp = ((dWr + br[j]) + dUr) + bur[j];
        const float up = dUh + buh[j];
        hh[jj] = (dWh + bh[j]) + rp * up;
        zp[jj] = ((zx + zh) + bz[j]) + buz[j];
    }
    __syncthreads();
    for (int jj = 0; jj < 16; ++jj) S.ln.hha[r][jt * 16 + jj] = hh[jj];
    __syncthreads();
    if (tid < 16) {
        float* a = S.ln.hha[tid];
        const float mu = np_row_sum512(a) / 512.0f;
        for (int k = 0; k < 512; ++k) { const float d = a[k] - mu; a[k] = d * d; }
        const float var = np_row_sum512(a) / 512.0f;
        const float ve  = var + 1e-5f;
        S.ln.mu[tid] = mu;
        S.ln.rstd[tid] = (float)(1.0 / sqrt((double)ve));
    }
    float sz = 0.f;
    for (int jj = 0; jj < 16; ++jj) sz += zp[jj];
#pragma unroll
    for (int off = 1; off < 32; off <<= 1) sz += __shfl_xor(sz, off, 32);
    const float muz = sz / 512.0f;
    float tz = 0.f;
    for (int jj = 0; jj < 16; ++jj) { const float d = zp[jj] - muz; tz = fmaf(d, d, tz); }
#pragma unroll
    for (int off = 1; off < 32; off <<= 1) tz += __shfl_xor(tz, off, 32);
    const float rstdz = 1.0f / sqrtf(tz / 512.0f + 1e-5f);
    __syncthreads();
    const float mu = S.ln.mu[r], rstd = S.ln.rstd[r];
    const float* hrow = h + ((size_t)(r0 + r) << 9);
    float* orow = out + ((size_t)(r0 + r) << 9);
    for (int jj = 0; jj < 16; ++jj) {
        const int j = jt * 16 + jj;
        const float d = hh[jj] - mu;
        const float v = ((d * rstd) * ln_g[1024 + j]) + ln_b[1024 + j];
        const float th = (float)tan((double)v);
        const float vz = ((zp[jj] - muz) * rstdz) * ln_g[j] + ln_b[j];
        const float zf = 1.0f / (1.0f + expf(-vz));
        orow[j] = (zf * hrow[j]) + (1.0f - zf) * th;
    }
}

extern "C" void kernel_launch(void* const* d_in, const int* in_sizes, int n_in,
                              void* d_out, int out_size, void* d_ws, size_t ws_size,
                              hipStream_t stream)
{
    (void)in_sizes; (void)n_in; (void)out_size;
    const float* x   = (const float*)d_in[0];
    const float* h   = (const float*)d_in[1];
    const float* Wz  = (const float*)d_in[2];
    const float* bz  = (const float*)d_in[3];
    const float* Uz  = (const float*)d_in[4];
    const float* buz = (const float*)d_in[5];
    const float* Wr  = (const float*)d_in[6];
    const float* br  = (const float*)d_in[7];
    const float* Ur  = (const float*)d_in[8];
    const float* bur = (const float*)d_in[9];
    const float* Wh  = (const float*)d_in[10];
    const float* bh  = (const float*)d_in[11];
    const float* Uh  = (const float*)d_in[12];
    const float* buh = (const float*)d_in[13];
    const float* lng = (const float*)d_in[14];
    const float* lnb = (const float*)d_in[15];
    float* out = (float*)d_out;

    if (ws_size >= (size_t)6 * 262144 * 4) {
        float* P = (float*)d_ws;
        hipLaunchKernelGGL(k_tr, dim3(1536), dim3(256), 0, stream,
                           Wr, Ur, Uh, Wh, Wz, Uz, P);
        hipLaunchKernelGGL(gru_fast, dim3(16384 / 8), dim3(TPB), 0, stream,
                           x, h, P, bz, buz, br, bur, bh, buh, lng, lnb, out);
    } else {
        hipLaunchKernelGGL(gru_np19, dim3(16384 / 16), dim3(TPB), 0, stream,
                           x, h, Wz, bz, Uz, buz, Wr, br, Ur, bur,
                           Wh, bh, Uh, buh, lng, lnb, out);
    }
}

// Round 25
// 673.275 us; speedup vs baseline: 1.4793x; 1.4793x over previous
//
#pragma clang fp contract(off)
#include <hip/hip_runtime.h>
#include <math.h>

// GRUCell + LN, B=16384, IN=H=512, fp32. PASSED numerics recipe (R19+):
//  * GEMM dots: per-element ONE ascending fused-FMA chain over k=0..511.
//  * hh-LN: unseeded symmetric pairwise sum512=(B0+B1)+(B2+B3), B=128-elem
//    npyv-AVX512 base; mean=sum/512; rstd=correctly-rounded (var+1e-5f)^-0.5.
//  * v=((hh-mu)*rstd)*g+b; tan via f64; out=(z*h)+((1-z)*th).
//  * z path relaxed (contraction-bounded).
//
// R26 perf: rounds 21-24 were L2/L3-BW bound at ~12-15 TB/s (traffic =
// nblocks x 6MB of weights; VALU fixes invisible). Fix: 32 ROWS/BLOCK,
// 512 blocks -> weight traffic 12.9 -> 3.2 GB (~250us at L3 BW), below the
// 328us packed-FMA floor. asm v_pk_fma_f32 kept (per-half IEEE fused,
// ascending-k order => bit-exact). 160 f32x2 accs -> ~200 VGPR, 2 waves/SIMD;
// LDS 128KB (x/h pair-interleaved); LDS reads are wave-uniform broadcasts.

#define TPB 512
typedef float f32x2 __attribute__((ext_vector_type(2)));
typedef float f32x4 __attribute__((ext_vector_type(4)));

// acc = a * broadcast(w.lo) + acc   (per-half fused)
__device__ __forceinline__ void pkfma_lo(f32x2& acc, f32x2 a, f32x2 w) {
    asm("v_pk_fma_f32 %0, %1, %2, %0 op_sel:[0,0,0] op_sel_hi:[1,0,1]"
        : "+v"(acc) : "v"(a), "v"(w));
}
// acc = a * broadcast(w.hi) + acc
__device__ __forceinline__ void pkfma_hi(f32x2& acc, f32x2 a, f32x2 w) {
    asm("v_pk_fma_f32 %0, %1, %2, %0 op_sel:[0,1,0] op_sel_hi:[1,1,1]"
        : "+v"(acc) : "v"(a), "v"(w));
}

// ---- numpy npyv-AVX512 pairwise base, n == 128 exactly ----
__device__ __forceinline__ float pw_avx512_128(const float* a) {
    float L[16];
#pragma unroll
    for (int l = 0; l < 16; ++l)
        L[l] = ((a[l] + a[16 + l]) + (a[32 + l] + a[48 + l]))
             + ((a[64 + l] + a[80 + l]) + (a[96 + l] + a[112 + l]));
    float s[8];
#pragma unroll
    for (int i = 0; i < 8; ++i) s[i] = L[i] + L[i + 8];
    float q[4];
#pragma unroll
    for (int i = 0; i < 4; ++i) q[i] = s[i] + s[i + 4];
    return (q[0] + q[2]) + (q[1] + q[3]);
}
__device__ float np_row_sum512(const float* a) {
    return (pw_avx512_128(a) + pw_avx512_128(a + 128))
         + (pw_avx512_128(a + 256) + pw_avx512_128(a + 384));
}

// ---- weight transpose: P[m][k4][j][kk] = W_m[j][4*k4+kk] ----
__global__ __launch_bounds__(256) void k_tr(
    const float* __restrict__ Wr, const float* __restrict__ Ur,
    const float* __restrict__ Uh, const float* __restrict__ Wh,
    const float* __restrict__ Wz, const float* __restrict__ Uz,
    float* __restrict__ P)
{
    const int idx = blockIdx.x * 256 + threadIdx.x;   // 6*65536 total
    const int m = idx >> 16;
    const int t = idx & 65535;
    const int k4 = t >> 9, j = t & 511;
    const float* W = (m == 0) ? Wr : (m == 1) ? Ur : (m == 2) ? Uh
                   : (m == 3) ? Wh : (m == 4) ? Wz : Uz;
    const float4 v = *(const float4*)(W + ((size_t)j << 9) + (k4 << 2));
    *(float4*)(P + ((size_t)m << 18) + (k4 << 11) + (j << 2)) = v;
}

// ================= fast kernel: 32 rows/block =================
__global__ __launch_bounds__(TPB, 1) void gru_fast(
    const float* __restrict__ x,  const float* __restrict__ h,
    const float* __restrict__ P,
    const float* __restrict__ bz, const float* __restrict__ buz,
    const float* __restrict__ br, const float* __restrict__ bur,
    const float* __restrict__ bh, const float* __restrict__ buh,
    const float* __restrict__ ln_g, const float* __restrict__ ln_b,
    float* __restrict__ out)
{
    __shared__ union {
        struct { float xs2[16][1024]; float hs2[16][1024]; } a;      // 128 KB
        struct { float hha[32][516]; float lnB[32][4];
                 float zsum[32][8]; float zsq[32][8];
                 float mu[32]; float rstd[32]; float muz[32]; float rstdz[32]; } b;
    } L;

    const int j  = threadIdx.x;
    const int r0 = blockIdx.x * 32;

    {   // stage 32 x,h rows pair-interleaved: xs2[rp][2k+half] = x[2rp+half][k]
        const float4* xg = (const float4*)(x + ((size_t)r0 << 9));
        const float4* hg = (const float4*)(h + ((size_t)r0 << 9));
#pragma unroll
        for (int t = 0; t < 8; ++t) {
            const int i = j + t * TPB;                // 0..4095
            const int row = i >> 7, c4 = i & 127;
            const int rp = row >> 1, half = row & 1;
            const int base = rp * 1024 + c4 * 8 + half;
            const float4 vx = xg[i];
            float* xd = &L.a.xs2[0][0];
            xd[base + 0] = vx.x; xd[base + 2] = vx.y;
            xd[base + 4] = vx.z; xd[base + 6] = vx.w;
            const float4 vh = hg[i];
            float* hd = &L.a.hs2[0][0];
            hd[base + 0] = vh.x; hd[base + 2] = vh.y;
            hd[base + 4] = vh.z; hd[base + 6] = vh.w;
        }
    }
    __syncthreads();

    const float* pWr = P;
    const float* pUr = P + 262144;
    const float* pUh = P + 524288;
    const float* pWh = P + 786432;
    const float* pWz = P + 1048576;
    const float* pUz = P + 1310720;

    const float brj = br[j], burj = bur[j], buhj = buh[j], bhj = bh[j];
    const float bzj = bz[j] + buz[j];                     // relaxed

    f32x2 aWr[16], aUr[16], aUh[16], aWh[16], aZ[16];
#pragma unroll
    for (int p = 0; p < 16; ++p) {
        aWr[p] = (f32x2)0.f; aUr[p] = (f32x2)0.f; aUh[p] = (f32x2)0.f;
        aWh[p] = (f32x2)0.f; aZ[p]  = (f32x2)0.f;
    }

    for (int k4 = 0; k4 < 128; ++k4) {
        const int off = (k4 << 11) + (j << 2);
        const f32x4 wr = *(const f32x4*)(pWr + off);
        const f32x4 ur = *(const f32x4*)(pUr + off);
        const f32x4 uh = *(const f32x4*)(pUh + off);
        const f32x4 wh = *(const f32x4*)(pWh + off);
        const f32x4 wz = *(const f32x4*)(pWz + off);
        const f32x4 uz = *(const f32x4*)(pUz + off);

        const f32x2 wrA = __builtin_shufflevector(wr, wr, 0, 1);
        const f32x2 wrB = __builtin_shufflevector(wr, wr, 2, 3);
        const f32x2 urA = __builtin_shufflevector(ur, ur, 0, 1);
        const f32x2 urB = __builtin_shufflevector(ur, ur, 2, 3);
        const f32x2 uhA = __builtin_shufflevector(uh, uh, 0, 1);
        const f32x2 uhB = __builtin_shufflevector(uh, uh, 2, 3);
        const f32x2 whA = __builtin_shufflevector(wh, wh, 0, 1);
        const f32x2 whB = __builtin_shufflevector(wh, wh, 2, 3);
        const f32x2 wzA = __builtin_shufflevector(wz, wz, 0, 1);
        const f32x2 wzB = __builtin_shufflevector(wz, wz, 2, 3);
        const f32x2 uzA = __builtin_shufflevector(uz, uz, 0, 1);
        const f32x2 uzB = __builtin_shufflevector(uz, uz, 2, 3);
#pragma unroll
        for (int p = 0; p < 16; ++p) {
            const float* xb = &L.a.xs2[p][k4 << 3];
            const float* hb = &L.a.hs2[p][k4 << 3];
            const f32x4 xA = *(const f32x4*)(xb);      // pairs k, k+1 (bcast)
            const f32x4 xB = *(const f32x4*)(xb + 4);  // pairs k+2, k+3
            const f32x4 hA = *(const f32x4*)(hb);
            const f32x4 hB = *(const f32x4*)(hb + 4);
            const f32x2 x0 = __builtin_shufflevector(xA, xA, 0, 1);
            const f32x2 x1 = __builtin_shufflevector(xA, xA, 2, 3);
            const f32x2 x2 = __builtin_shufflevector(xB, xB, 0, 1);
            const f32x2 x3 = __builtin_shufflevector(xB, xB, 2, 3);
            const f32x2 h0 = __builtin_shufflevector(hA, hA, 0, 1);
            const f32x2 h1 = __builtin_shufflevector(hA, hA, 2, 3);
            const f32x2 h2 = __builtin_shufflevector(hB, hB, 0, 1);
            const f32x2 h3 = __builtin_shufflevector(hB, hB, 2, 3);
            // ascending-k fused chains, identical per-row rounding order
            pkfma_lo(aWr[p], x0, wrA); pkfma_hi(aWr[p], x1, wrA);
            pkfma_lo(aWr[p], x2, wrB); pkfma_hi(aWr[p], x3, wrB);
            pkfma_lo(aUr[p], h0, urA); pkfma_hi(aUr[p], h1, urA);
            pkfma_lo(aUr[p], h2, urB); pkfma_hi(aUr[p], h3, urB);
            pkfma_lo(aUh[p], h0, uhA); pkfma_hi(aUh[p], h1, uhA);
            pkfma_lo(aUh[p], h2, uhB); pkfma_hi(aUh[p], h3, uhB);
            pkfma_lo(aWh[p], x0, whA); pkfma_hi(aWh[p], x1, whA);
            pkfma_lo(aWh[p], x2, whB); pkfma_hi(aWh[p], x3, whB);
            pkfma_lo(aZ[p],  x0, wzA); pkfma_hi(aZ[p],  x1, wzA);
            pkfma_lo(aZ[p],  x2, wzB); pkfma_hi(aZ[p],  x3, wzB);
            pkfma_lo(aZ[p],  h0, uzA); pkfma_hi(aZ[p],  h1, uzA);
            pkfma_lo(aZ[p],  h2, uzB); pkfma_hi(aZ[p],  h3, uzB);
        }
    }

    // glue (exact scalar orders)
    float hh[32], zp[32];
#pragma unroll
    for (int p = 0; p < 16; ++p) {
#pragma unroll
        for (int half = 0; half < 2; ++half) {
            const float dWr = half ? aWr[p].y : aWr[p].x;
            const float dUr = half ? aUr[p].y : aUr[p].x;
            const float dUh = half ? aUh[p].y : aUh[p].x;
            const float dWh = half ? aWh[p].y : aWh[p].x;
            const float dZ  = half ? aZ[p].y  : aZ[p].x;
            const float rp2 = ((dWr + brj) + dUr) + burj;   // exact order
            const float up  = dUh + buhj;
            hh[p * 2 + half] = (dWh + bhj) + rp2 * up;
            zp[p * 2 + half] = dZ + bzj;
        }
    }
    __syncthreads();   // xs2/hs2 dead; union b becomes live

#pragma unroll
    for (int r = 0; r < 32; ++r) L.b.hha[r][j] = hh[r];
    {   // relaxed z stats: wave-level shfl reduce -> per-wave partials
        const int wid = j >> 6, lane = j & 63;
#pragma unroll
        for (int r = 0; r < 32; ++r) {
            float s = zp[r], q = zp[r] * zp[r];
#pragma unroll
            for (int o = 1; o < 64; o <<= 1) { s += __shfl_xor(s, o); q += __shfl_xor(q, o); }
            if (lane == 0) { L.b.zsum[r][wid] = s; L.b.zsq[r][wid] = q; }
        }
    }
    __syncthreads();

    // LN stage 1: 128 threads compute the four 128-blocks per row (exact base)
    if (j < 128) {
        const int r = j >> 2, b = j & 3;
        L.b.lnB[r][b] = pw_avx512_128(&L.b.hha[r][b * 128]);
    } else if (j < 160) {
        const int r = j - 128;   // relaxed z finalize
        float s = 0.f, q = 0.f;
#pragma unroll
        for (int w = 0; w < 8; ++w) { s += L.b.zsum[r][w]; q += L.b.zsq[r][w]; }
        const float m = s / 512.0f;
        L.b.muz[r]   = m;
        L.b.rstdz[r] = 1.0f / sqrtf(q / 512.0f - m * m + 1e-5f);
    }
    __syncthreads();
    if (j < 32) {
        const float sum = (L.b.lnB[j][0] + L.b.lnB[j][1])
                        + (L.b.lnB[j][2] + L.b.lnB[j][3]);   // exact tree
        L.b.mu[j] = sum / 512.0f;
    }
    __syncthreads();
#pragma unroll
    for (int r = 0; r < 32; ++r) {
        const float d = hh[r] - L.b.mu[r];
        L.b.hha[r][j] = d * d;
    }
    __syncthreads();
    if (j < 128) {
        const int r = j >> 2, b = j & 3;
        L.b.lnB[r][b] = pw_avx512_128(&L.b.hha[r][b * 128]);
    }
    __syncthreads();
    if (j < 32) {
        const float var = ((L.b.lnB[j][0] + L.b.lnB[j][1])
                         + (L.b.lnB[j][2] + L.b.lnB[j][3])) / 512.0f;
        const float ve  = var + 1e-5f;
        L.b.rstd[j] = (float)(1.0 / sqrt((double)ve));   // correctly-rounded
    }
    __syncthreads();

    const float g2 = ln_g[1024 + j], b2 = ln_b[1024 + j];
    const float g0 = ln_g[j],        b0 = ln_b[j];
#pragma unroll
    for (int r = 0; r < 32; ++r) {
        const float d  = hh[r] - L.b.mu[r];
        const float t  = d * L.b.rstd[r];
        const float v  = (t * g2) + b2;                 // exact order
        const float th = (float)tan((double)v);
        const float vz = ((zp[r] - L.b.muz[r]) * L.b.rstdz[r]) * g0 + b0;
        const float zf = 1.0f / (1.0f + expf(-vz));
        const float hv = h[((size_t)(r0 + r) << 9) + j];
        out[((size_t)(r0 + r) << 9) + j] = (zf * hv) + (1.0f - zf) * th;
    }
}

// ================= fallback (R19, proven) =================
__device__ __forceinline__ void sweep3c(const float* __restrict__ sa,
                                        const float* __restrict__ wA,
                                        const float* __restrict__ wB,
                                        const float* __restrict__ wC,
                                        float& dA, float& dB, float& dC)
{
    float a = 0.f, b = 0.f, c = 0.f;
    for (int k4 = 0; k4 < 128; ++k4) {
        const int k0 = k4 << 2;
        const float4 xv = *(const float4*)(sa + k0);
        const float4 av = *(const float4*)(wA + k0);
        const float4 bv = *(const float4*)(wB + k0);
        const float4 cv = *(const float4*)(wC + k0);
        a = fmaf(xv.x, av.x, a); a = fmaf(xv.y, av.y, a);
        a = fmaf(xv.z, av.z, a); a = fmaf(xv.w, av.w, a);
        b = fmaf(xv.x, bv.x, b); b = fmaf(xv.y, bv.y, b);
        b = fmaf(xv.z, bv.z, b); b = fmaf(xv.w, bv.w, b);
        c = fmaf(xv.x, cv.x, c); c = fmaf(xv.y, cv.y, c);
        c = fmaf(xv.z, cv.z, c); c = fmaf(xv.w, cv.w, c);
    }
    dA = a; dB = b; dC = c;
}

__global__ __launch_bounds__(TPB) void gru_np19(
    const float* __restrict__ x,  const float* __restrict__ h,
    const float* __restrict__ Wz, const float* __restrict__ bz,
    const float* __restrict__ Uz, const float* __restrict__ buz,
    const float* __restrict__ Wr, const float* __restrict__ br,
    const float* __restrict__ Ur, const float* __restrict__ bur,
    const float* __restrict__ Wh, const float* __restrict__ bh,
    const float* __restrict__ Uh, const float* __restrict__ buh,
    const float* __restrict__ ln_g, const float* __restrict__ ln_b,
    float* __restrict__ out)
{
    __shared__ union {
        float xh[2][16][512];
        struct { float hha[16][522]; float mu[16]; float rstd[16]; } ln;
    } S;
    const int tid = threadIdx.x;
    const int r = tid >> 5, jt = tid & 31;
    const int r0 = blockIdx.x * 16;
    {
        const float4* xg = (const float4*)(x + ((size_t)r0 << 9));
        const float4* hg = (const float4*)(h + ((size_t)r0 << 9));
        float4* xd = (float4*)S.xh[0];
        float4* hd = (float4*)S.xh[1];
        for (int idx = tid; idx < 2048; idx += TPB) { xd[idx] = xg[idx]; hd[idx] = hg[idx]; }
    }
    __syncthreads();
    const float* xs = S.xh[0][r];
    const float* hs = S.xh[1][r];
    float hh[16], zp[16];
    for (int jj = 0; jj < 16; ++jj) {
        const int j = jt * 16 + jj;
        const size_t jb = (size_t)j << 9;
        float dWr, dWh, zx;
        sweep3c(xs, Wr + jb, Wh + jb, Wz + jb, dWr, dWh, zx);
        float dUr, dUh, zh;
        sweep3c(hs, Ur + jb, Uh + jb, Uz + jb, dUr, dUh, zh);
        const float rp = ((dWr + br[j]) + dUr) + bur[j];
        const float up = dUh + buh[j];
        hh[jj] = (dWh + bh[j]) + rp * up;
        zp[jj] = ((zx + zh) + bz[j]) + buz[j];
    }
    __syncthreads();
    for (int jj = 0; jj < 16; ++jj) S.ln.hha[r][jt * 16 + jj] = hh[jj];
    __syncthreads();
    if (tid < 16) {
        float* a = S.ln.hha[tid];
        const float mu = np_row_sum512(a) / 512.0f;
        for (int k = 0; k < 512; ++k) { const float d = a[k] - mu; a[k] = d * d; }
        const float var = np_row_sum512(a) / 512.0f;
        const float ve  = var + 1e-5f;
        S.ln.mu[tid] = mu;
        S.ln.rstd[tid] = (float)(1.0 / sqrt((double)ve));
    }
    float sz = 0.f;
    for (int jj = 0; jj < 16; ++jj) sz += zp[jj];
#pragma unroll
    for (int off = 1; off < 32; off <<= 1) sz += __shfl_xor(sz, off, 32);
    const float muz = sz / 512.0f;
    float tz = 0.f;
    for (int jj = 0; jj < 16; ++jj) { const float d = zp[jj] - muz; tz = fmaf(d, d, tz); }
#pragma unroll
    for (int off = 1; off < 32; off <<= 1) tz += __shfl_xor(tz, off, 32);
    const float rstdz = 1.0f / sqrtf(tz / 512.0f + 1e-5f);
    __syncthreads();
    const float mu = S.ln.mu[r], rstd = S.ln.rstd[r];
    const float* hrow = h + ((size_t)(r0 + r) << 9);
    float* orow = out + ((size_t)(r0 + r) << 9);
    for (int jj = 0; jj < 16; ++jj) {
        const int j = jt * 16 + jj;
        const float d = hh[jj] - mu;
        const float v = ((d * rstd) * ln_g[1024 + j]) + ln_b[1024 + j];
        const float th = (float)tan((double)v);
        const float vz = ((zp[jj] - muz) * rstdz) * ln_g[j] + ln_b[j];
        const float zf = 1.0f / (1.0f + expf(-vz));
        orow[j] = (zf * hrow[j]) + (1.0f - zf) * th;
    }
}

extern "C" void kernel_launch(void* const* d_in, const int* in_sizes, int n_in,
                              void* d_out, int out_size, void* d_ws, size_t ws_size,
                              hipStream_t stream)
{
    (void)in_sizes; (void)n_in; (void)out_size;
    const float* x   = (const float*)d_in[0];
    const float* h   = (const float*)d_in[1];
    const float* Wz  = (const float*)d_in[2];
    const float* bz  = (const float*)d_in[3];
    const float* Uz  = (const float*)d_in[4];
    const float* buz = (const float*)d_in[5];
    const float* Wr  = (const float*)d_in[6];
    const float* br  = (const float*)d_in[7];
    const float* Ur  = (const float*)d_in[8];
    const float* bur = (const float*)d_in[9];
    const float* Wh  = (const float*)d_in[10];
    const float* bh  = (const float*)d_in[11];
    const float* Uh  = (const float*)d_in[12];
    const float* buh = (const float*)d_in[13];
    const float* lng = (const float*)d_in[14];
    const float* lnb = (const float*)d_in[15];
    float* out = (float*)d_out;

    if (ws_size >= (size_t)6 * 262144 * 4) {
        float* P = (float*)d_ws;
        hipLaunchKernelGGL(k_tr, dim3(1536), dim3(256), 0, stream,
                           Wr, Ur, Uh, Wh, Wz, Uz, P);
        hipLaunchKernelGGL(gru_fast, dim3(16384 / 32), dim3(TPB), 0, stream,
                           x, h, P, bz, buz, br, bur, bh, buh, lng, lnb, out);
    } else {
        hipLaunchKernelGGL(gru_np19, dim3(16384 / 16), dim3(TPB), 0, stream,
                           x, h, Wz, bz, Uz, buz, Wr, br, Ur, bur,
                           Wh, bh, Uh, buh, lng, lnb, out);
    }
}